// Round 11
// baseline (759.679 us; speedup 1.0000x reference)
//
#include <hip/hip_runtime.h>
#include <hip/hip_fp16.h>
#include <hip/hip_cooperative_groups.h>

namespace cg = cooperative_groups;

// Circuit: 4-layer sum-product network, real semiring.
// R11: cooperative mega-kernel, hardened. R10's coop launch silently failed
// (no fallback, err discarded). Now: occupancy-queried grid (residency check
// cannot fail on sizing), grid-stride phase bodies robust to any grid size,
// and a deterministic fallback to the proven R9 5-kernel path if the coop
// launch errors. Phase bodies = best-known variants.

#define NTHR 256
#define WBITS_H 20     // 1M halfs = 2MB window

typedef __attribute__((ext_vector_type(4))) int   iv4;
typedef __attribute__((ext_vector_type(4))) float fv4;
typedef __attribute__((ext_vector_type(4))) unsigned int uv4;

__device__ __forceinline__ iv4 nt_load4(const int* p) {
    return __builtin_nontemporal_load((const iv4*)p);
}

__device__ __forceinline__ float decode16(const __half* __restrict__ xp, int idx) {
    int k = (idx - 2) >> 1;
    k = k < 0 ? 0 : k;
    float v = __half2float(xp[k]);
    v = (idx & 1) ? 1.0f - v : v;
    if (idx < 2) v = (float)idx;
    return v;
}

// ==================== cooperative mega-kernel ====================
__global__ __launch_bounds__(NTHR, 8)
void mega_kernel(const float* __restrict__ x_pos,
                 const int* __restrict__ ix_in0,
                 const int* __restrict__ ix_in1,
                 const int* __restrict__ ix_out1,
                 const int* __restrict__ ix_in2,
                 const int* __restrict__ ix_in3,
                 const int* __restrict__ ix_out3,
                 float* __restrict__ out,
                 __half* __restrict__ y0,
                 float* __restrict__ y1,
                 float* __restrict__ y2,
                 __half* __restrict__ x16,
                 int NV, int M0, int E1, int M1, int M2, int E3, int M3) {
    cg::grid_group grid = cg::this_grid();
    const int nTh  = gridDim.x * blockDim.x;
    const int gtid = blockIdx.x * blockDim.x + threadIdx.x;
    const int lane = threadIdx.x & 63;

    // -------- phase 0: cvt x_pos -> fp16 + zero y1/out --------
    {
        int n4 = NV / 4;
        for (int t = gtid; t < n4; t += nTh) {
            fv4 f = __builtin_nontemporal_load((const fv4*)(x_pos + 4 * (size_t)t));
            __half2 lo = __floats2half2_rn(f.x, f.y);
            __half2 hi = __floats2half2_rn(f.z, f.w);
            unsigned int* xu = (unsigned int*)x16;
            xu[2 * t]     = *(const unsigned int*)&lo;
            xu[2 * t + 1] = *(const unsigned int*)&hi;
        }
        int nz1 = M1 / 4;
        for (int t = gtid; t < nz1; t += nTh) {
            fv4 z = {0.f, 0.f, 0.f, 0.f};
            __builtin_nontemporal_store(z, (fv4*)(y1 + 4 * (size_t)t));
        }
        int nzo = M3 / 4;
        for (int t = gtid; t < nzo; t += nTh) {
            fv4 z = {0.f, 0.f, 0.f, 0.f};
            __builtin_nontemporal_store(z, (fv4*)(out + 4 * (size_t)t));
        }
    }
    grid.sync();

    // -------- phase 1: L0 prod8 from fp16 table --------
    {
        int nT = M0 / 8;
        for (int t = gtid; t < nT; t += nTh) {
            iv4 p0 = nt_load4(ix_in0 + 16 * (size_t)t);
            iv4 p1 = nt_load4(ix_in0 + 16 * (size_t)t + 4);
            iv4 p2 = nt_load4(ix_in0 + 16 * (size_t)t + 8);
            iv4 p3 = nt_load4(ix_in0 + 16 * (size_t)t + 12);
            float a0 = decode16(x16, p0.x), b0 = decode16(x16, p0.y);
            float a1 = decode16(x16, p0.z), b1 = decode16(x16, p0.w);
            float a2 = decode16(x16, p1.x), b2 = decode16(x16, p1.y);
            float a3 = decode16(x16, p1.z), b3 = decode16(x16, p1.w);
            float a4 = decode16(x16, p2.x), b4 = decode16(x16, p2.y);
            float a5 = decode16(x16, p2.z), b5 = decode16(x16, p2.w);
            float a6 = decode16(x16, p3.x), b6 = decode16(x16, p3.y);
            float a7 = decode16(x16, p3.z), b7 = decode16(x16, p3.w);
            __half2 h0 = __floats2half2_rn(a0 * b0, a1 * b1);
            __half2 h1 = __floats2half2_rn(a2 * b2, a3 * b3);
            __half2 h2 = __floats2half2_rn(a4 * b4, a5 * b5);
            __half2 h3 = __floats2half2_rn(a6 * b6, a7 * b7);
            uv4 r;
            r.x = *(const unsigned int*)&h0;
            r.y = *(const unsigned int*)&h1;
            r.z = *(const unsigned int*)&h2;
            r.w = *(const unsigned int*)&h3;
            __builtin_nontemporal_store(r, (uv4*)((unsigned int*)y0 + 4 * (size_t)t));
        }
    }
    grid.sync();

    // -------- phase 2: L1 sum, NS=4 window convoy + dynamic tail --------
    {
        const int NS = 4, NWIN = 4;
        int nT4 = E1 / 4;
        iv4    a[NS];
        float4 v[NS];
        bool   act[NS];
        #pragma unroll
        for (int s = 0; s < NS; ++s) {
            int t = s * nTh + gtid;
            act[s] = (t < nT4);
            a[s] = act[s] ? nt_load4(ix_in1 + 4 * (size_t)t) : (iv4){-1, -1, -1, -1};
            v[s] = make_float4(0.f, 0.f, 0.f, 0.f);
        }
        #pragma unroll
        for (int w = 0; w < NWIN; ++w) {
            #pragma unroll
            for (int s = 0; s < NS; ++s) {
                if ((a[s].x >> WBITS_H) == w) v[s].x = __half2float(y0[a[s].x]);
                if ((a[s].y >> WBITS_H) == w) v[s].y = __half2float(y0[a[s].y]);
                if ((a[s].z >> WBITS_H) == w) v[s].z = __half2float(y0[a[s].z]);
                if ((a[s].w >> WBITS_H) == w) v[s].w = __half2float(y0[a[s].w]);
            }
        }
        #pragma unroll
        for (int s = 0; s < NS; ++s) {
            int seg = -1; float val = 0.f;
            if (act[s]) {
                int t = s * nTh + gtid;
                iv4 sg = nt_load4(ix_out1 + 4 * (size_t)t);
                int cur = sg.x; float acc = v[s].x;
                if (sg.y == cur) acc += v[s].y; else { atomicAdd(&y1[cur], acc); cur = sg.y; acc = v[s].y; }
                if (sg.z == cur) acc += v[s].z; else { atomicAdd(&y1[cur], acc); cur = sg.z; acc = v[s].z; }
                if (sg.w == cur) acc += v[s].w; else { atomicAdd(&y1[cur], acc); cur = sg.w; acc = v[s].w; }
                seg = cur; val = acc;
            }
            #pragma unroll
            for (int off = 1; off < 64; off <<= 1) {
                float vv = __shfl_up(val, off, 64);
                int   ss = __shfl_up(seg, off, 64);
                if (lane >= off && ss == seg) val += vv;
            }
            int seg_next = __shfl_down(seg, 1, 64);
            bool is_last = (lane == 63) || (seg_next != seg);
            if (seg >= 0 && is_last) atomicAdd(&y1[seg], val);
        }
        // dynamic tail for grids smaller than 2048 blocks (straight gathers)
        for (int t = NS * nTh + gtid; t < nT4; t += nTh) {
            iv4 at = nt_load4(ix_in1 + 4 * (size_t)t);
            iv4 sg = nt_load4(ix_out1 + 4 * (size_t)t);
            float v0 = __half2float(y0[at.x]);
            float v1 = __half2float(y0[at.y]);
            float v2 = __half2float(y0[at.z]);
            float v3 = __half2float(y0[at.w]);
            int cur = sg.x; float acc = v0;
            if (sg.y == cur) acc += v1; else { atomicAdd(&y1[cur], acc); cur = sg.y; acc = v1; }
            if (sg.z == cur) acc += v2; else { atomicAdd(&y1[cur], acc); cur = sg.z; acc = v2; }
            if (sg.w == cur) acc += v3; else { atomicAdd(&y1[cur], acc); cur = sg.w; acc = v3; }
            atomicAdd(&y1[cur], acc);
        }
    }
    grid.sync();

    // -------- phase 3: L2 prod2 --------
    {
        int nT = M2 / 2;
        for (int t = gtid; t < nT; t += nTh) {
            iv4 p = nt_load4(ix_in2 + 4 * (size_t)t);
            float a0 = y1[p.x], b0 = y1[p.y];
            float a1 = y1[p.z], b1 = y1[p.w];
            float2 r; r.x = a0 * b0; r.y = a1 * b1;
            *(float2*)(y2 + 2 * (size_t)t) = r;
        }
    }
    grid.sync();

    // -------- phase 4: L3 sum4 --------
    {
        int nT4 = E3 / 4;
        for (int t = gtid; t < nT4; t += nTh) {
            iv4 a  = nt_load4(ix_in3  + 4 * (size_t)t);
            iv4 sg = nt_load4(ix_out3 + 4 * (size_t)t);
            float v0 = y2[a.x], v1 = y2[a.y], v2 = y2[a.z], v3 = y2[a.w];
            int cur = sg.x; float acc = v0;
            if (sg.y == cur) acc += v1; else { atomicAdd(&out[cur], acc); cur = sg.y; acc = v1; }
            if (sg.z == cur) acc += v2; else { atomicAdd(&out[cur], acc); cur = sg.z; acc = v2; }
            if (sg.w == cur) acc += v3; else { atomicAdd(&out[cur], acc); cur = sg.w; acc = v3; }
            // wave-scan across lanes of this iteration's run
            int seg = cur; float val = acc;
            #pragma unroll
            for (int off = 1; off < 64; off <<= 1) {
                float vv = __shfl_up(val, off, 64);
                int   ss = __shfl_up(seg, off, 64);
                if (lane >= off && ss == seg) val += vv;
            }
            int seg_next = __shfl_down(seg, 1, 64);
            bool is_last = (lane == 63) || (seg_next != seg);
            if (is_last) atomicAdd(&out[seg], val);
        }
    }
}

// ==================== fallback path (R9, proven 252us) ====================
__global__ void init_kernel(const float* __restrict__ in, unsigned int* __restrict__ x16,
                            float* __restrict__ y1, float* __restrict__ out,
                            int n4, int nz1, int nzo) {
    int t = blockIdx.x * blockDim.x + threadIdx.x;
    if (t < n4) {
        fv4 f = __builtin_nontemporal_load((const fv4*)(in + 4 * (size_t)t));
        __half2 lo = __floats2half2_rn(f.x, f.y);
        __half2 hi = __floats2half2_rn(f.z, f.w);
        x16[2 * t]     = *(const unsigned int*)&lo;
        x16[2 * t + 1] = *(const unsigned int*)&hi;
    }
    if (t < nz1) {
        fv4 z = {0.f, 0.f, 0.f, 0.f};
        __builtin_nontemporal_store(z, (fv4*)(y1 + 4 * (size_t)t));
    }
    if (t < nzo) {
        fv4 z = {0.f, 0.f, 0.f, 0.f};
        __builtin_nontemporal_store(z, (fv4*)(out + 4 * (size_t)t));
    }
}

__global__ void layer0_prod8_kernel(const __half* __restrict__ x16,
                                    const int* __restrict__ ix,
                                    unsigned int* __restrict__ out16, int nT) {
    int t = blockIdx.x * blockDim.x + threadIdx.x;
    if (t >= nT) return;
    iv4 p0 = nt_load4(ix + 16 * (size_t)t);
    iv4 p1 = nt_load4(ix + 16 * (size_t)t + 4);
    iv4 p2 = nt_load4(ix + 16 * (size_t)t + 8);
    iv4 p3 = nt_load4(ix + 16 * (size_t)t + 12);
    float a0 = decode16(x16, p0.x), b0 = decode16(x16, p0.y);
    float a1 = decode16(x16, p0.z), b1 = decode16(x16, p0.w);
    float a2 = decode16(x16, p1.x), b2 = decode16(x16, p1.y);
    float a3 = decode16(x16, p1.z), b3 = decode16(x16, p1.w);
    float a4 = decode16(x16, p2.x), b4 = decode16(x16, p2.y);
    float a5 = decode16(x16, p2.z), b5 = decode16(x16, p2.w);
    float a6 = decode16(x16, p3.x), b6 = decode16(x16, p3.y);
    float a7 = decode16(x16, p3.z), b7 = decode16(x16, p3.w);
    __half2 h0 = __floats2half2_rn(a0 * b0, a1 * b1);
    __half2 h1 = __floats2half2_rn(a2 * b2, a3 * b3);
    __half2 h2 = __floats2half2_rn(a4 * b4, a5 * b5);
    __half2 h3 = __floats2half2_rn(a6 * b6, a7 * b7);
    uv4 r;
    r.x = *(const unsigned int*)&h0;
    r.y = *(const unsigned int*)&h1;
    r.z = *(const unsigned int*)&h2;
    r.w = *(const unsigned int*)&h3;
    __builtin_nontemporal_store(r, (uv4*)(out16 + 4 * (size_t)t));
}

template<int NS, int NWIN>
__global__ __launch_bounds__(NTHR)
void sum_win_h_kernel(const __half* __restrict__ vin,
                      const int* __restrict__ ix_in,
                      const int* __restrict__ ix_out,
                      float* __restrict__ out, int nT4) {
    const int nTh  = gridDim.x * blockDim.x;
    const int gtid = blockIdx.x * blockDim.x + threadIdx.x;
    const int lane = threadIdx.x & 63;

    iv4    a[NS];
    iv4    sg[NS];
    float4 v[NS];
    bool   act[NS];
    #pragma unroll
    for (int s = 0; s < NS; ++s) {
        int t = s * nTh + gtid;
        act[s] = (t < nT4);
        if (act[s]) {
            a[s]  = nt_load4(ix_in  + 4 * (size_t)t);
            sg[s] = nt_load4(ix_out + 4 * (size_t)t);
        } else {
            a[s]  = (iv4){-1, -1, -1, -1};
            sg[s] = (iv4){-1, -1, -1, -1};
        }
        v[s] = make_float4(0.f, 0.f, 0.f, 0.f);
    }
    #pragma unroll
    for (int w = 0; w < NWIN; ++w) {
        #pragma unroll
        for (int s = 0; s < NS; ++s) {
            if ((a[s].x >> WBITS_H) == w) v[s].x = __half2float(vin[a[s].x]);
            if ((a[s].y >> WBITS_H) == w) v[s].y = __half2float(vin[a[s].y]);
            if ((a[s].z >> WBITS_H) == w) v[s].z = __half2float(vin[a[s].z]);
            if ((a[s].w >> WBITS_H) == w) v[s].w = __half2float(vin[a[s].w]);
        }
    }
    #pragma unroll
    for (int s = 0; s < NS; ++s) {
        int seg = -1; float val = 0.f;
        if (act[s]) {
            int cur = sg[s].x; float acc = v[s].x;
            if (sg[s].y == cur) acc += v[s].y; else { atomicAdd(&out[cur], acc); cur = sg[s].y; acc = v[s].y; }
            if (sg[s].z == cur) acc += v[s].z; else { atomicAdd(&out[cur], acc); cur = sg[s].z; acc = v[s].z; }
            if (sg[s].w == cur) acc += v[s].w; else { atomicAdd(&out[cur], acc); cur = sg[s].w; acc = v[s].w; }
            seg = cur; val = acc;
        }
        #pragma unroll
        for (int off = 1; off < 64; off <<= 1) {
            float vv = __shfl_up(val, off, 64);
            int   ss = __shfl_up(seg, off, 64);
            if (lane >= off && ss == seg) val += vv;
        }
        int seg_next = __shfl_down(seg, 1, 64);
        bool is_last = (lane == 63) || (seg_next != seg);
        if (act[s] && is_last) atomicAdd(&out[seg], val);
    }
}

__global__ void sum4_f32_kernel(const float* __restrict__ vin,
                                const int* __restrict__ ix_in,
                                const int* __restrict__ ix_out,
                                float* __restrict__ out, int nT4) {
    int t = blockIdx.x * blockDim.x + threadIdx.x;
    int lane = threadIdx.x & 63;
    int seg = -1; float val = 0.f;
    if (t < nT4) {
        iv4 a  = nt_load4(ix_in  + 4 * (size_t)t);
        iv4 sg = nt_load4(ix_out + 4 * (size_t)t);
        float v0 = vin[a.x], v1 = vin[a.y], v2 = vin[a.z], v3 = vin[a.w];
        int cur = sg.x; float acc = v0;
        if (sg.y == cur) acc += v1; else { atomicAdd(&out[cur], acc); cur = sg.y; acc = v1; }
        if (sg.z == cur) acc += v2; else { atomicAdd(&out[cur], acc); cur = sg.z; acc = v2; }
        if (sg.w == cur) acc += v3; else { atomicAdd(&out[cur], acc); cur = sg.w; acc = v3; }
        seg = cur; val = acc;
    }
    #pragma unroll
    for (int off = 1; off < 64; off <<= 1) {
        float vv = __shfl_up(val, off, 64);
        int   ss = __shfl_up(seg, off, 64);
        if (lane >= off && ss == seg) val += vv;
    }
    int seg_next = __shfl_down(seg, 1, 64);
    bool is_last = (lane == 63) || (seg_next != seg);
    if (t < nT4 && is_last) atomicAdd(&out[seg], val);
}

__global__ void prod2_kernel(const float* __restrict__ vin,
                             const int* __restrict__ ix,
                             float2* __restrict__ out, int nT) {
    int t = blockIdx.x * blockDim.x + threadIdx.x;
    if (t >= nT) return;
    iv4 p = nt_load4(ix + 4 * (size_t)t);
    float a0 = vin[p.x], b0 = vin[p.y];
    float a1 = vin[p.z], b1 = vin[p.w];
    float2 r; r.x = a0 * b0; r.y = a1 * b1;
    out[t] = r;
}

extern "C" void kernel_launch(void* const* d_in, const int* in_sizes, int n_in,
                              void* d_out, int out_size, void* d_ws, size_t ws_size,
                              hipStream_t stream) {
    const float* x_pos  = (const float*)d_in[0];
    const int*   ix_in0 = (const int*)d_in[1];
    const int*   ix_in1 = (const int*)d_in[2];
    const int*   ix_out1= (const int*)d_in[3];
    const int*   ix_in2 = (const int*)d_in[4];
    const int*   ix_in3 = (const int*)d_in[5];
    const int*   ix_out3= (const int*)d_in[6];
    float* out = (float*)d_out;

    int NV = in_sizes[0];       // 2,000,000
    int M0 = in_sizes[1] / 2;   // 4,000,000
    int E1 = in_sizes[2];       // 8,000,000
    int M1 = 1000000;
    int M2 = in_sizes[4] / 2;   // 500,000
    int E3 = in_sizes[5];       // 1,000,000
    int M3 = out_size;          // 125,000

    char* ws = (char*)d_ws;
    __half* y0  = (__half*)(ws);                            //  8 MB
    float*  y1  = (float*)(ws + (size_t)8  * 1024 * 1024);  //  4 MB
    float*  y2  = (float*)(ws + (size_t)12 * 1024 * 1024);  //  2 MB
    __half* x16 = (__half*)(ws + (size_t)14 * 1024 * 1024); //  4 MB

    // --- try the cooperative mega-kernel with an occupancy-sized grid ---
    int blocksPerCU = 0;
    hipError_t qerr = hipOccupancyMaxActiveBlocksPerMultiprocessor(
        &blocksPerCU, (const void*)mega_kernel, NTHR, 0);
    if (qerr != hipSuccess || blocksPerCU < 1) blocksPerCU = 1;
    int nBlk = blocksPerCU * 256;          // 256 CUs
    if (nBlk > 2048) nBlk = 2048;

    void* args[] = {
        (void*)&x_pos, (void*)&ix_in0, (void*)&ix_in1, (void*)&ix_out1,
        (void*)&ix_in2, (void*)&ix_in3, (void*)&ix_out3, (void*)&out,
        (void*)&y0, (void*)&y1, (void*)&y2, (void*)&x16,
        (void*)&NV, (void*)&M0, (void*)&E1, (void*)&M1,
        (void*)&M2, (void*)&E3, (void*)&M3,
    };
    hipError_t lerr = hipLaunchCooperativeKernel(
        (const void*)mega_kernel, dim3(nBlk), dim3(NTHR), args, 0, stream);

    if (lerr == hipSuccess) return;

    // --- fallback: proven R9 5-kernel pipeline ---
    const int B = 256;
    int n4  = NV / 4;
    int nz1 = M1 / 4;
    int nzo = M3 / 4;
    init_kernel<<<(n4 + B - 1) / B, B, 0, stream>>>(
        x_pos, (unsigned int*)x16, y1, out, n4, nz1, nzo);

    int t0 = M0 / 8;
    layer0_prod8_kernel<<<(t0 + B - 1) / B, B, 0, stream>>>(
        x16, ix_in0, (unsigned int*)y0, t0);

    int t1 = E1 / 4;
    sum_win_h_kernel<4, 4><<<2048, NTHR, 0, stream>>>(
        y0, ix_in1, ix_out1, y1, t1);

    int t2 = M2 / 2;
    prod2_kernel<<<(t2 + B - 1) / B, B, 0, stream>>>(
        y1, ix_in2, (float2*)y2, t2);

    int t3 = E3 / 4;
    sum4_f32_kernel<<<(t3 + B - 1) / B, B, 0, stream>>>(
        y2, ix_in3, ix_out3, out, t3);
}

// Round 12
// 290.015 us; speedup vs baseline: 2.6194x; 2.6194x over previous
//
#include <hip/hip_runtime.h>
#include <hip/hip_fp16.h>

// Circuit: 4-layer sum-product network, real semiring.
// R12: 3-dispatch pipeline (coop fusion dead: grid.sync ~220us/barrier on
// 8-XCD MI355X — R11 measured 1053us single-kernel).
//  D1: L0 prod8 gathering f32 x_pos DIRECTLY (request-bound, extra bytes
//      free; cvt pass + its dependency removed) + zeroing y1/out in spare
//      threads. y0 written fp16.
//  D2: L1 segment-sum, NS=4 x 2MB-window convoy over fp16 y0 (at the
//      measured scattered-request wall ~4.7cyc/req/CU; FETCH 87MB).
//  D3: L2+L3 fused: gather ix_in2 pairs per L3 edge, y1[a]*y1[b] on the
//      fly, segmented scan + atomics into out. y2 eliminated.

#define NTHR 256
#define WBITS_H 20     // 1M halfs = 2MB window

typedef __attribute__((ext_vector_type(4))) int   iv4;
typedef __attribute__((ext_vector_type(2))) int   iv2;
typedef __attribute__((ext_vector_type(4))) float fv4;
typedef __attribute__((ext_vector_type(4))) unsigned int uv4;

__device__ __forceinline__ iv4 nt_load4(const int* p) {
    return __builtin_nontemporal_load((const iv4*)p);
}
__device__ __forceinline__ iv2 nt_load2(const int* p) {
    return __builtin_nontemporal_load((const iv2*)p);
}

// decode virtual input straight from f32 x_pos
__device__ __forceinline__ float decodef(const float* __restrict__ xp, int idx) {
    int k = (idx - 2) >> 1;
    k = k < 0 ? 0 : k;                 // safe unconditional load (ILP)
    float v = xp[k];
    v = (idx & 1) ? 1.0f - v : v;
    if (idx < 2) v = (float)idx;       // constants override
    return v;
}

// ---------- D1: L0 prod8 (direct f32 gathers) + zero y1/out ----------
__global__ void l0_fused_kernel(const float* __restrict__ x_pos,
                                const int* __restrict__ ix,
                                unsigned int* __restrict__ out16,
                                float* __restrict__ y1, float* __restrict__ out,
                                int nT, int nz1, int nzo) {
    int t = blockIdx.x * blockDim.x + threadIdx.x;
    // zeroing for the downstream sum layers (independent of the products)
    if (t < nz1) {
        fv4 z = {0.f, 0.f, 0.f, 0.f};
        __builtin_nontemporal_store(z, (fv4*)(y1 + 4 * (size_t)t));
    }
    if (t < nzo) {
        fv4 z = {0.f, 0.f, 0.f, 0.f};
        __builtin_nontemporal_store(z, (fv4*)(out + 4 * (size_t)t));
    }
    if (t >= nT) return;
    iv4 p0 = nt_load4(ix + 16 * (size_t)t);
    iv4 p1 = nt_load4(ix + 16 * (size_t)t + 4);
    iv4 p2 = nt_load4(ix + 16 * (size_t)t + 8);
    iv4 p3 = nt_load4(ix + 16 * (size_t)t + 12);
    float a0 = decodef(x_pos, p0.x), b0 = decodef(x_pos, p0.y);
    float a1 = decodef(x_pos, p0.z), b1 = decodef(x_pos, p0.w);
    float a2 = decodef(x_pos, p1.x), b2 = decodef(x_pos, p1.y);
    float a3 = decodef(x_pos, p1.z), b3 = decodef(x_pos, p1.w);
    float a4 = decodef(x_pos, p2.x), b4 = decodef(x_pos, p2.y);
    float a5 = decodef(x_pos, p2.z), b5 = decodef(x_pos, p2.w);
    float a6 = decodef(x_pos, p3.x), b6 = decodef(x_pos, p3.y);
    float a7 = decodef(x_pos, p3.z), b7 = decodef(x_pos, p3.w);
    __half2 h0 = __floats2half2_rn(a0 * b0, a1 * b1);
    __half2 h1 = __floats2half2_rn(a2 * b2, a3 * b3);
    __half2 h2 = __floats2half2_rn(a4 * b4, a5 * b5);
    __half2 h3 = __floats2half2_rn(a6 * b6, a7 * b7);
    uv4 r;
    r.x = *(const unsigned int*)&h0;
    r.y = *(const unsigned int*)&h1;
    r.z = *(const unsigned int*)&h2;
    r.w = *(const unsigned int*)&h3;
    __builtin_nontemporal_store(r, (uv4*)(out16 + 4 * (size_t)t));
}

// ---------- D2: L1 segment-sum over fp16 y0, window-outer convoy ----------
template<int NS, int NWIN>
__global__ __launch_bounds__(NTHR)
void sum_win_h_kernel(const __half* __restrict__ vin,
                      const int* __restrict__ ix_in,
                      const int* __restrict__ ix_out,
                      float* __restrict__ out, int nT4) {
    const int nTh  = gridDim.x * blockDim.x;
    const int gtid = blockIdx.x * blockDim.x + threadIdx.x;
    const int lane = threadIdx.x & 63;

    iv4    a[NS];
    iv4    sg[NS];
    float4 v[NS];
    bool   act[NS];
    #pragma unroll
    for (int s = 0; s < NS; ++s) {
        int t = s * nTh + gtid;
        act[s] = (t < nT4);
        if (act[s]) {
            a[s]  = nt_load4(ix_in  + 4 * (size_t)t);
            sg[s] = nt_load4(ix_out + 4 * (size_t)t);
        } else {
            a[s]  = (iv4){-1, -1, -1, -1};
            sg[s] = (iv4){-1, -1, -1, -1};
        }
        v[s] = make_float4(0.f, 0.f, 0.f, 0.f);
    }
    #pragma unroll
    for (int w = 0; w < NWIN; ++w) {
        #pragma unroll
        for (int s = 0; s < NS; ++s) {
            if ((a[s].x >> WBITS_H) == w) v[s].x = __half2float(vin[a[s].x]);
            if ((a[s].y >> WBITS_H) == w) v[s].y = __half2float(vin[a[s].y]);
            if ((a[s].z >> WBITS_H) == w) v[s].z = __half2float(vin[a[s].z]);
            if ((a[s].w >> WBITS_H) == w) v[s].w = __half2float(vin[a[s].w]);
        }
    }
    #pragma unroll
    for (int s = 0; s < NS; ++s) {
        int seg = -1; float val = 0.f;
        if (act[s]) {
            int cur = sg[s].x; float acc = v[s].x;
            if (sg[s].y == cur) acc += v[s].y; else { atomicAdd(&out[cur], acc); cur = sg[s].y; acc = v[s].y; }
            if (sg[s].z == cur) acc += v[s].z; else { atomicAdd(&out[cur], acc); cur = sg[s].z; acc = v[s].z; }
            if (sg[s].w == cur) acc += v[s].w; else { atomicAdd(&out[cur], acc); cur = sg[s].w; acc = v[s].w; }
            seg = cur; val = acc;
        }
        #pragma unroll
        for (int off = 1; off < 64; off <<= 1) {
            float vv = __shfl_up(val, off, 64);
            int   ss = __shfl_up(seg, off, 64);
            if (lane >= off && ss == seg) val += vv;
        }
        int seg_next = __shfl_down(seg, 1, 64);
        bool is_last = (lane == 63) || (seg_next != seg);
        if (act[s] && is_last) atomicAdd(&out[seg], val);
    }
}

// ---------- D3: fused L2+L3 ----------
// L3 edge e sums y2[j], j=ix_in3[e]; y2[j]=y1[ix_in2[2j]]*y1[ix_in2[2j+1]].
__global__ void l2l3_fused_kernel(const float* __restrict__ y1,
                                  const int* __restrict__ ix_in2,
                                  const int* __restrict__ ix_in3,
                                  const int* __restrict__ ix_out3,
                                  float* __restrict__ out, int nT4) {
    int t = blockIdx.x * blockDim.x + threadIdx.x;
    int lane = threadIdx.x & 63;
    int seg = -1; float val = 0.f;
    if (t < nT4) {
        iv4 e  = nt_load4(ix_in3  + 4 * (size_t)t);
        iv4 sg = nt_load4(ix_out3 + 4 * (size_t)t);
        iv2 q0 = nt_load2(ix_in2 + 2 * (size_t)e.x);
        iv2 q1 = nt_load2(ix_in2 + 2 * (size_t)e.y);
        iv2 q2 = nt_load2(ix_in2 + 2 * (size_t)e.z);
        iv2 q3 = nt_load2(ix_in2 + 2 * (size_t)e.w);
        float v0 = y1[q0.x] * y1[q0.y];
        float v1 = y1[q1.x] * y1[q1.y];
        float v2 = y1[q2.x] * y1[q2.y];
        float v3 = y1[q3.x] * y1[q3.y];
        int cur = sg.x; float acc = v0;
        if (sg.y == cur) acc += v1; else { atomicAdd(&out[cur], acc); cur = sg.y; acc = v1; }
        if (sg.z == cur) acc += v2; else { atomicAdd(&out[cur], acc); cur = sg.z; acc = v2; }
        if (sg.w == cur) acc += v3; else { atomicAdd(&out[cur], acc); cur = sg.w; acc = v3; }
        seg = cur; val = acc;
    }
    #pragma unroll
    for (int off = 1; off < 64; off <<= 1) {
        float vv = __shfl_up(val, off, 64);
        int   ss = __shfl_up(seg, off, 64);
        if (lane >= off && ss == seg) val += vv;
    }
    int seg_next = __shfl_down(seg, 1, 64);
    bool is_last = (lane == 63) || (seg_next != seg);
    if (t < nT4 && is_last) atomicAdd(&out[seg], val);
}

extern "C" void kernel_launch(void* const* d_in, const int* in_sizes, int n_in,
                              void* d_out, int out_size, void* d_ws, size_t ws_size,
                              hipStream_t stream) {
    const float* x_pos  = (const float*)d_in[0];
    const int*   ix_in0 = (const int*)d_in[1];
    const int*   ix_in1 = (const int*)d_in[2];
    const int*   ix_out1= (const int*)d_in[3];
    const int*   ix_in2 = (const int*)d_in[4];
    const int*   ix_in3 = (const int*)d_in[5];
    const int*   ix_out3= (const int*)d_in[6];
    float* out = (float*)d_out;

    const int M0 = in_sizes[1] / 2;   // 4,000,000
    const int E1 = in_sizes[2];       // 8,000,000
    const int M1 = 1000000;
    const int E3 = in_sizes[5];       // 1,000,000
    const int M3 = out_size;          // 125,000

    char* ws = (char*)d_ws;
    __half* y0 = (__half*)(ws);                            //  8 MB
    float*  y1 = (float*)(ws + (size_t)8 * 1024 * 1024);   //  4 MB

    const int B = NTHR;

    // D1: L0 prod8 + zero y1/out (500,000 threads)
    int t0  = M0 / 8;
    int nz1 = M1 / 4;
    int nzo = M3 / 4;
    l0_fused_kernel<<<(t0 + B - 1) / B, B, 0, stream>>>(
        x_pos, ix_in0, (unsigned int*)y0, y1, out, t0, nz1, nzo);

    // D2: L1, fp16 source 8MB -> 4 x 2MB windows, NS=4 covers 2M slots
    int t1 = E1 / 4;
    sum_win_h_kernel<4, 4><<<2048, B, 0, stream>>>(
        y0, ix_in1, ix_out1, y1, t1);

    // D3: fused L2+L3 (250,000 threads)
    int t3 = E3 / 4;
    l2l3_fused_kernel<<<(t3 + B - 1) / B, B, 0, stream>>>(
        y1, ix_in2, ix_in3, ix_out3, out, t3);
}

// Round 13
// 253.383 us; speedup vs baseline: 2.9981x; 1.1446x over previous
//
#include <hip/hip_runtime.h>
#include <hip/hip_fp16.h>

// Circuit: 4-layer sum-product network, real semiring.
// R13 = R9 verbatim (best measured: 252.6us). Map of closed avenues:
//  - L1 segment-sum: 72us across 6 variants while FETCH fell 408->87MB
//    => outstanding-request/latency wall (~5.5cyc/line/CU), not bytes.
//  - L0 via 4MB fp16 table: same wall (~60us); direct f32 gather (R12)
//    doubled footprint -> 79us. cvt pass is ~8us, worth it.
//  - Coop mega-kernel: grid.sync ~220us/barrier on 8 XCDs (R11) — dead.
//  - L2+L3 fusion: dependent index chain on 250k threads regressed (R12).
//  - Dispatch overhead ~4-5us each; ~90us of bench time is harness-fixed.
// Pipeline: init(cvt+zeros) -> L0 prod8(table) -> L1 convoy -> L2 -> L3.

#define NTHR 256
#define WBITS_H 20     // 1M halfs = 2MB window

typedef __attribute__((ext_vector_type(4))) int   iv4;
typedef __attribute__((ext_vector_type(4))) float fv4;
typedef __attribute__((ext_vector_type(4))) unsigned int uv4;

__device__ __forceinline__ iv4 nt_load4(const int* p) {
    return __builtin_nontemporal_load((const iv4*)p);
}

__device__ __forceinline__ float decode16(const __half* __restrict__ xp, int idx) {
    int k = (idx - 2) >> 1;
    k = k < 0 ? 0 : k;                 // safe unconditional load (ILP)
    float v = __half2float(xp[k]);
    v = (idx & 1) ? 1.0f - v : v;
    if (idx < 2) v = (float)idx;       // constants override
    return v;
}

// ---------- D1: cvt x_pos -> fp16 table + zero y1/out ----------
__global__ void init_kernel(const float* __restrict__ in, unsigned int* __restrict__ x16,
                            float* __restrict__ y1, float* __restrict__ out,
                            int n4, int nz1, int nzo) {
    int t = blockIdx.x * blockDim.x + threadIdx.x;
    if (t < n4) {
        fv4 f = __builtin_nontemporal_load((const fv4*)(in + 4 * (size_t)t));
        __half2 lo = __floats2half2_rn(f.x, f.y);
        __half2 hi = __floats2half2_rn(f.z, f.w);
        x16[2 * t]     = *(const unsigned int*)&lo;
        x16[2 * t + 1] = *(const unsigned int*)&hi;
    }
    if (t < nz1) {
        fv4 z = {0.f, 0.f, 0.f, 0.f};
        __builtin_nontemporal_store(z, (fv4*)(y1 + 4 * (size_t)t));
    }
    if (t < nzo) {
        fv4 z = {0.f, 0.f, 0.f, 0.f};
        __builtin_nontemporal_store(z, (fv4*)(out + 4 * (size_t)t));
    }
}

// ---------- D2: L0 prod8 from fp16 table ----------
__global__ void layer0_prod8_kernel(const __half* __restrict__ x16,
                                    const int* __restrict__ ix,
                                    unsigned int* __restrict__ out16, int nT) {
    int t = blockIdx.x * blockDim.x + threadIdx.x;
    if (t >= nT) return;
    iv4 p0 = nt_load4(ix + 16 * (size_t)t);
    iv4 p1 = nt_load4(ix + 16 * (size_t)t + 4);
    iv4 p2 = nt_load4(ix + 16 * (size_t)t + 8);
    iv4 p3 = nt_load4(ix + 16 * (size_t)t + 12);
    float a0 = decode16(x16, p0.x), b0 = decode16(x16, p0.y);
    float a1 = decode16(x16, p0.z), b1 = decode16(x16, p0.w);
    float a2 = decode16(x16, p1.x), b2 = decode16(x16, p1.y);
    float a3 = decode16(x16, p1.z), b3 = decode16(x16, p1.w);
    float a4 = decode16(x16, p2.x), b4 = decode16(x16, p2.y);
    float a5 = decode16(x16, p2.z), b5 = decode16(x16, p2.w);
    float a6 = decode16(x16, p3.x), b6 = decode16(x16, p3.y);
    float a7 = decode16(x16, p3.z), b7 = decode16(x16, p3.w);
    __half2 h0 = __floats2half2_rn(a0 * b0, a1 * b1);
    __half2 h1 = __floats2half2_rn(a2 * b2, a3 * b3);
    __half2 h2 = __floats2half2_rn(a4 * b4, a5 * b5);
    __half2 h3 = __floats2half2_rn(a6 * b6, a7 * b7);
    uv4 r;
    r.x = *(const unsigned int*)&h0;
    r.y = *(const unsigned int*)&h1;
    r.z = *(const unsigned int*)&h2;
    r.w = *(const unsigned int*)&h3;
    __builtin_nontemporal_store(r, (uv4*)(out16 + 4 * (size_t)t));
}

// ---------- D3: L1 segment-sum over fp16 y0, window-outer convoy ----------
template<int NS, int NWIN>
__global__ __launch_bounds__(NTHR)
void sum_win_h_kernel(const __half* __restrict__ vin,
                      const int* __restrict__ ix_in,
                      const int* __restrict__ ix_out,
                      float* __restrict__ out, int nT4) {
    const int nTh  = gridDim.x * blockDim.x;
    const int gtid = blockIdx.x * blockDim.x + threadIdx.x;
    const int lane = threadIdx.x & 63;

    iv4    a[NS];
    iv4    sg[NS];
    float4 v[NS];
    bool   act[NS];
    #pragma unroll
    for (int s = 0; s < NS; ++s) {
        int t = s * nTh + gtid;
        act[s] = (t < nT4);
        if (act[s]) {
            a[s]  = nt_load4(ix_in  + 4 * (size_t)t);
            sg[s] = nt_load4(ix_out + 4 * (size_t)t);
        } else {
            a[s]  = (iv4){-1, -1, -1, -1};
            sg[s] = (iv4){-1, -1, -1, -1};
        }
        v[s] = make_float4(0.f, 0.f, 0.f, 0.f);
    }
    #pragma unroll
    for (int w = 0; w < NWIN; ++w) {
        #pragma unroll
        for (int s = 0; s < NS; ++s) {
            if ((a[s].x >> WBITS_H) == w) v[s].x = __half2float(vin[a[s].x]);
            if ((a[s].y >> WBITS_H) == w) v[s].y = __half2float(vin[a[s].y]);
            if ((a[s].z >> WBITS_H) == w) v[s].z = __half2float(vin[a[s].z]);
            if ((a[s].w >> WBITS_H) == w) v[s].w = __half2float(vin[a[s].w]);
        }
    }
    #pragma unroll
    for (int s = 0; s < NS; ++s) {
        int seg = -1; float val = 0.f;
        if (act[s]) {
            int cur = sg[s].x; float acc = v[s].x;
            if (sg[s].y == cur) acc += v[s].y; else { atomicAdd(&out[cur], acc); cur = sg[s].y; acc = v[s].y; }
            if (sg[s].z == cur) acc += v[s].z; else { atomicAdd(&out[cur], acc); cur = sg[s].z; acc = v[s].z; }
            if (sg[s].w == cur) acc += v[s].w; else { atomicAdd(&out[cur], acc); cur = sg[s].w; acc = v[s].w; }
            seg = cur; val = acc;
        }
        #pragma unroll
        for (int off = 1; off < 64; off <<= 1) {
            float vv = __shfl_up(val, off, 64);
            int   ss = __shfl_up(seg, off, 64);
            if (lane >= off && ss == seg) val += vv;
        }
        int seg_next = __shfl_down(seg, 1, 64);
        bool is_last = (lane == 63) || (seg_next != seg);
        if (act[s] && is_last) atomicAdd(&out[seg], val);
    }
}

// ---------- D4: L2 prod2 ----------
__global__ void prod2_kernel(const float* __restrict__ vin,
                             const int* __restrict__ ix,
                             float2* __restrict__ out, int nT) {
    int t = blockIdx.x * blockDim.x + threadIdx.x;
    if (t >= nT) return;
    iv4 p = nt_load4(ix + 4 * (size_t)t);
    float a0 = vin[p.x], b0 = vin[p.y];
    float a1 = vin[p.z], b1 = vin[p.w];
    float2 r; r.x = a0 * b0; r.y = a1 * b1;
    out[t] = r;
}

// ---------- D5: L3 sum4 over f32 y2 ----------
__global__ void sum4_f32_kernel(const float* __restrict__ vin,
                                const int* __restrict__ ix_in,
                                const int* __restrict__ ix_out,
                                float* __restrict__ out, int nT4) {
    int t = blockIdx.x * blockDim.x + threadIdx.x;
    int lane = threadIdx.x & 63;
    int seg = -1; float val = 0.f;
    if (t < nT4) {
        iv4 a  = nt_load4(ix_in  + 4 * (size_t)t);
        iv4 sg = nt_load4(ix_out + 4 * (size_t)t);
        float v0 = vin[a.x], v1 = vin[a.y], v2 = vin[a.z], v3 = vin[a.w];
        int cur = sg.x; float acc = v0;
        if (sg.y == cur) acc += v1; else { atomicAdd(&out[cur], acc); cur = sg.y; acc = v1; }
        if (sg.z == cur) acc += v2; else { atomicAdd(&out[cur], acc); cur = sg.z; acc = v2; }
        if (sg.w == cur) acc += v3; else { atomicAdd(&out[cur], acc); cur = sg.w; acc = v3; }
        seg = cur; val = acc;
    }
    #pragma unroll
    for (int off = 1; off < 64; off <<= 1) {
        float vv = __shfl_up(val, off, 64);
        int   ss = __shfl_up(seg, off, 64);
        if (lane >= off && ss == seg) val += vv;
    }
    int seg_next = __shfl_down(seg, 1, 64);
    bool is_last = (lane == 63) || (seg_next != seg);
    if (t < nT4 && is_last) atomicAdd(&out[seg], val);
}

extern "C" void kernel_launch(void* const* d_in, const int* in_sizes, int n_in,
                              void* d_out, int out_size, void* d_ws, size_t ws_size,
                              hipStream_t stream) {
    const float* x_pos  = (const float*)d_in[0];
    const int*   ix_in0 = (const int*)d_in[1];
    const int*   ix_in1 = (const int*)d_in[2];
    const int*   ix_out1= (const int*)d_in[3];
    const int*   ix_in2 = (const int*)d_in[4];
    const int*   ix_in3 = (const int*)d_in[5];
    const int*   ix_out3= (const int*)d_in[6];
    float* out = (float*)d_out;

    const int NV = in_sizes[0];       // 2,000,000
    const int M0 = in_sizes[1] / 2;   // 4,000,000
    const int E1 = in_sizes[2];       // 8,000,000
    const int M1 = 1000000;
    const int M2 = in_sizes[4] / 2;   // 500,000
    const int E3 = in_sizes[5];       // 1,000,000
    const int M3 = out_size;          // 125,000

    char* ws = (char*)d_ws;
    __half* y0  = (__half*)(ws);                            //  8 MB
    float*  y1  = (float*)(ws + (size_t)8  * 1024 * 1024);  //  4 MB
    float*  y2  = (float*)(ws + (size_t)12 * 1024 * 1024);  //  2 MB
    __half* x16 = (__half*)(ws + (size_t)14 * 1024 * 1024); //  4 MB

    const int B = NTHR;

    // D1: cvt + zeros
    int n4  = NV / 4;
    int nz1 = M1 / 4;
    int nzo = M3 / 4;
    init_kernel<<<(n4 + B - 1) / B, B, 0, stream>>>(
        x_pos, (unsigned int*)x16, y1, out, n4, nz1, nzo);

    // D2: L0 prod8 from 4MB fp16 table
    int t0 = M0 / 8;
    layer0_prod8_kernel<<<(t0 + B - 1) / B, B, 0, stream>>>(
        x16, ix_in0, (unsigned int*)y0, t0);

    // D3: L1, fp16 source 8MB -> 4 x 2MB windows, NS=4 covers 2M slots
    int t1 = E1 / 4;
    sum_win_h_kernel<4, 4><<<2048, B, 0, stream>>>(
        y0, ix_in1, ix_out1, y1, t1);

    // D4: L2 prod2
    int t2 = M2 / 2;
    prod2_kernel<<<(t2 + B - 1) / B, B, 0, stream>>>(
        y1, ix_in2, (float2*)y2, t2);

    // D5: L3 sum4
    int t3 = E3 / 4;
    sum4_f32_kernel<<<(t3 + B - 1) / B, B, 0, stream>>>(
        y2, ix_in3, ix_out3, out, t3);
}